// Round 9
// baseline (205.644 us; speedup 1.0000x reference)
//
#include <hip/hip_runtime.h>
#include <hip/hip_bf16.h>

// Dims (fixed): B=32, L=512, D=32, H=256, E=8, PLEN*O=3072, LAT=256, PD=64, NPROT=16

typedef __hip_bfloat16 bf16;
typedef unsigned short u16;
typedef __attribute__((ext_vector_type(8))) short s8v;   // 8 bf16 MFMA A/B frag
typedef __attribute__((ext_vector_type(4))) float f4v;   // MFMA C/D frag

#define MFMA_BF16(a,b,c) __builtin_amdgcn_mfma_f32_16x16x32_bf16(a,b,c,0,0,0)

#if __has_builtin(__builtin_amdgcn_sqrtf)
#define FSQRT(x) __builtin_amdgcn_sqrtf(x)
#else
#define FSQRT(x) sqrtf(x)
#endif
#if __has_builtin(__builtin_amdgcn_exp2f)
#define FEXP2(x) __builtin_amdgcn_exp2f(x)
#else
#define FEXP2(x) exp2f(x)
#endif
#if __has_builtin(__builtin_amdgcn_logf)
#define FLOG2(x) __builtin_amdgcn_logf(x)
#else
#define FLOG2(x) log2f(x)
#endif

// gw blob u16 offsets
#define GWF1 0
#define GW2  57344
#define GWF2 122880
#define GWP  139264
#define GPROT 143360
#define GWG  144384
// total 146432 u16

__device__ __forceinline__ float bf2f(u16 u){
  union{ unsigned u32; float f; } w; w.u32 = ((unsigned)u) << 16; return w.f;
}
__device__ __forceinline__ u16 f2bf(float f){
  bf16 h = __float2bfloat16(f);
  union{ bf16 b; u16 u; } w; w.b = h; return w.u;
}
__device__ __forceinline__ u16 f2bf_fast(float f){
  union{ float f; unsigned u; } v; v.f = f;
  unsigned r = v.u + 0x7FFFu + ((v.u >> 16) & 1u);
  return (u16)(r >> 16);
}
__device__ __forceinline__ float ldg_(const void* p, long long i, bool bf){
  float r;
  if(bf) r = bf2f(((const u16*)p)[i]);
  else   r = ((const float*)p)[i];
  return r;
}
__device__ __forceinline__ bool bfflag(const void* ln_g){
  return ((const u16*)ln_g)[0] == 0x3F80;
}

// ---------------------------------------------------------------------------
// KS1 (fused input stage): [0,1024) k1_fft; [1024,4111) kt_all;
// [4111,4623) kx_cvt. All parts read only kernel inputs. grid 4623.
// Xr/Xi stored only for bins 0..256 (rows 257..511 are never read:
// k5a uses bins 0..255, contrib uses bin 256 — Hermitian symmetry).
// ---------------------------------------------------------------------------
__global__ __launch_bounds__(256) void ks1(const void* __restrict__ ln_g,
    const void* __restrict__ x,
    const void* __restrict__ Win, const void* __restrict__ Wfft,
    const void* __restrict__ W1, const void* __restrict__ Whead,
    const void* __restrict__ Wf1, const void* __restrict__ W2,
    const void* __restrict__ Wf2, const void* __restrict__ Wp,
    const void* __restrict__ prot, const void* __restrict__ Wg,
    u16* __restrict__ xbf,
    u16* __restrict__ WinTg, u16* __restrict__ WfftTg,
    u16* __restrict__ W1Tg, u16* __restrict__ WheadTg,
    u16* __restrict__ gw,
    u16* __restrict__ Xr, u16* __restrict__ Xi, float* __restrict__ cf){
  const bool bf = bfflag(ln_g);
  __shared__ float xs[512], re[512], im[512];
  __shared__ float twr[256], twi[256];
  __shared__ float r0s[4], r1s[4], r2s[4], r3s[4];
  __shared__ u16 tile[64][72];
  int BX = blockIdx.x, t = threadIdx.x;

  if(BX < 1024){
    // ---------------- k1_fft ----------------
    int b = BX >> 5, d = BX & 31;
    {
      float rev = -(float)t * (1.f/512.f);
#if __has_builtin(__builtin_amdgcn_cosf) && __has_builtin(__builtin_amdgcn_sinf)
      twr[t] = __builtin_amdgcn_cosf(rev);
      twi[t] = __builtin_amdgcn_sinf(rev);
#else
      float ang = rev * 6.283185307179586f;
      twr[t] = cosf(ang); twi[t] = sinf(ang);
#endif
    }
    for(int i=t;i<512;i+=256){
      float v = ldg_(x, (long long)(b*512+i)*32 + d, bf);
      xs[i] = v;
      re[__brev((unsigned)i) >> 23] = v;
      im[i] = 0.f;
    }
    __syncthreads();
    float s=0.f, s2=0.f, mn=3.0e38f, mx=-3.0e38f;
    for(int i=t;i<512;i+=256){ float v=xs[i]; s+=v; s2+=v*v; mn=fminf(mn,v); mx=fmaxf(mx,v); }
    #pragma unroll
    for(int o=32;o>0;o>>=1){
      s  += __shfl_down(s,o);  s2 += __shfl_down(s2,o);
      mn = fminf(mn,__shfl_down(mn,o)); mx = fmaxf(mx,__shfl_down(mx,o));
    }
    int wv = t>>6, ln = t&63;
    if(ln==0){ r0s[wv]=s; r1s[wv]=s2; r2s[wv]=mn; r3s[wv]=mx; }
    __syncthreads();
    if(t==0){
      float S =r0s[0]+r0s[1]+r0s[2]+r0s[3];
      float S2=r1s[0]+r1s[1]+r1s[2]+r1s[3];
      float MN=fminf(fminf(r2s[0],r2s[1]),fminf(r2s[2],r2s[3]));
      float MX=fmaxf(fmaxf(r3s[0],r3s[1]),fmaxf(r3s[2],r3s[3]));
      float mean = S*(1.f/512.f);
      float var  = (S2 - S*S*(1.f/512.f))*(1.f/511.f);   // ddof=1
      float* c = cf + b*224;
      c[d]      = mean;
      c[32+d]   = sqrtf(fmaxf(var,0.f));
      c[64+d]   = MN;
      c[96+d]   = MX;
      float dv = xs[511]-xs[0];
      c[128+d]  = dv*(1.f/511.f);
      c[160+d]  = dv*(1.f/512.f);
    }
    for(int st=1; st<=9; ++st){
      __syncthreads();
      int m = 1<<st, half = m>>1;
      int grp = t >> (st-1);
      int k   = t & (half-1);
      int i1 = grp*m + k, i2 = i1 + half;
      int ti_ = k << (9-st);
      float cs = twr[ti_], sn = twi[ti_];
      float ar=re[i1], ai=im[i1], br=re[i2], bi=im[i2];
      float tr = cs*br - sn*bi;
      float ti = cs*bi + sn*br;
      re[i1]=ar+tr; im[i1]=ai+ti;
      re[i2]=ar-tr; im[i2]=ai-ti;
    }
    __syncthreads();
    float ms=0.f;
    for(int i=t;i<512;i+=256){
      float rr=re[i], ii=im[i];
      if(i <= 256){
        long long o = (long long)(b*512+i)*32 + d;
        Xr[o]=f2bf(rr); Xi[o]=f2bf(ii);
      }
      ms += FSQRT(rr*rr+ii*ii);
    }
    #pragma unroll
    for(int o=32;o>0;o>>=1) ms += __shfl_down(ms,o);
    if(ln==0) r0s[wv]=ms;
    __syncthreads();
    if(t==0) cf[b*224 + 192 + d] = (r0s[0]+r0s[1]+r0s[2]+r0s[3])*(1.f/512.f);
    return;
  }
  if(BX < 4111){
    // ---------------- kt_all ----------------
    int bx = BX - 1024;
    if(bx < 256){
      int i = bx*256 + t;
      int e = i >> 13, r = i & 8191;
      int c = r >> 5, d = r & 31;
      WinTg[i] = f2bf(ldg_(Win, (long long)e*8192 + d*256 + c, bf));
      return;
    }
    if(bx < 384){
      int idx = bx - 256;
      int e = idx >> 4, tl = idx & 15, kb = tl >> 2, cb = tl & 3;
      if(bf){
        for(int q=0;q<16;q++){
          int G = q*256 + t; int ki = G >> 6, ci = G & 63;
          tile[ci][ki] = ((const u16*)Wfft)[(long long)e*65536 + (long long)(kb*64+ki)*256 + cb*64+ci];
        }
      } else {
        for(int q=0;q<16;q++){
          int G = q*256 + t; int ki = G >> 6, ci = G & 63;
          tile[ci][ki] = f2bf(((const float*)Wfft)[(long long)e*65536 + (long long)(kb*64+ki)*256 + cb*64+ci]);
        }
      }
      __syncthreads();
      for(int q=0;q<16;q++){
        int G = q*256 + t; int ci = G >> 6, ki = G & 63;
        WfftTg[(long long)e*65536 + (long long)(cb*64+ci)*256 + kb*64+ki] = tile[ci][ki];
      }
      return;
    }
    if(bx < 1408){
      int idx = bx - 384;
      int kb = idx & 255, nb = idx >> 8;
      if(bf){
        for(int q=0;q<16;q++){
          int G = q*256 + t; int ki = G >> 6, ni = G & 63;
          tile[ni][ki] = ((const u16*)W1)[(long long)(kb*64+ki)*256 + nb*64+ni];
        }
      } else {
        for(int q=0;q<16;q++){
          int G = q*256 + t; int ki = G >> 6, ni = G & 63;
          tile[ni][ki] = f2bf(((const float*)W1)[(long long)(kb*64+ki)*256 + nb*64+ni]);
        }
      }
      __syncthreads();
      for(int q=0;q<16;q++){
        int G = q*256 + t; int ni = G >> 6, ki = G & 63;
        W1Tg[(long long)(nb*64+ni)*16384 + kb*64+ki] = tile[ni][ki];
      }
      return;
    }
    if(bx < 2944){
      int idx = bx - 1408;
      int e = idx / 192, rem = idx % 192;
      int kb = rem / 48, nb = rem % 48;
      if(bf){
        for(int q=0;q<16;q++){
          int G = q*256 + t; int ki = G >> 6, ni = G & 63;
          tile[ni][ki] = ((const u16*)Whead)[(long long)e*786432 + (long long)(kb*64+ki)*3072 + nb*64+ni];
        }
      } else {
        for(int q=0;q<16;q++){
          int G = q*256 + t; int ki = G >> 6, ni = G & 63;
          tile[ni][ki] = f2bf(((const float*)Whead)[(long long)e*786432 + (long long)(kb*64+ki)*3072 + nb*64+ni]);
        }
      }
      __syncthreads();
      for(int q=0;q<16;q++){
        int G = q*256 + t; int ni = G >> 6, ki = G & 63;
        WheadTg[(long long)e*786432 + (long long)(nb*64+ni)*256 + kb*64+ki] = tile[ni][ki];
      }
      return;
    }
    // gw blob copies
    {
      int c = bx - 2944;
      const void* src; int dstbase, blkoff;
      if(c < 56)      { src=Wf1;  dstbase=GWF1;  blkoff=c; }
      else if(c <120) { src=W2;   dstbase=GW2;   blkoff=c-56; }
      else if(c <136) { src=Wf2;  dstbase=GWF2;  blkoff=c-120; }
      else if(c <140) { src=Wp;   dstbase=GWP;   blkoff=c-136; }
      else if(c <141) { src=prot; dstbase=GPROT; blkoff=0; }
      else            { src=Wg;   dstbase=GWG;   blkoff=c-141; }
      int i = blkoff*1024 + t*4;
      if(bf){
        ushort4 v = *(const ushort4*)((const u16*)src + i);
        *(ushort4*)(gw + dstbase + i) = v;
      } else {
        float4 f = *(const float4*)((const float*)src + i);
        ushort4 v; v.x=f2bf(f.x); v.y=f2bf(f.y); v.z=f2bf(f.z); v.w=f2bf(f.w);
        *(ushort4*)(gw + dstbase + i) = v;
      }
    }
    return;
  }
  // ---------------- kx_cvt ----------------
  {
    int i = ((BX-4111)*256 + t)*4;
    if(bf){
      ushort4 v = *(const ushort4*)((const u16*)x + i);
      *(ushort4*)(xbf+i) = v;
    } else {
      float4 f = *(const float4*)((const float*)x + i);
      ushort4 v; v.x=f2bf(f.x); v.y=f2bf(f.y); v.z=f2bf(f.z); v.w=f2bf(f.w);
      *(ushort4*)(xbf+i) = v;
    }
  }
}

// ---------------------------------------------------------------------------
// KS2 (fused stage 2): [0,64) k3a psum GEMM; [64,1088) k5a magnitude;
// [1088,1120) h1 = relu(cf@Wf1+bf1); [1120,1376) contrib (bin-256 fixup).
// grid 1376.
// ---------------------------------------------------------------------------
__global__ __launch_bounds__(256) void ks2(const void* __restrict__ ln_g,
    const u16* __restrict__ xbf, const u16* __restrict__ Xr, const u16* __restrict__ Xi,
    const u16* __restrict__ WinTg, const u16* __restrict__ W1Tg,
    const u16* __restrict__ gw, const float* __restrict__ cf,
    const void* __restrict__ bf1, const void* __restrict__ b_in,
    const void* __restrict__ b_fft, const void* __restrict__ a_logit,
    const void* __restrict__ Win, const void* __restrict__ Wfft,
    float* __restrict__ psum, u16* __restrict__ hmagG,
    float* __restrict__ h1f, float* __restrict__ contrib){
  const bool bf = bfflag(ln_g);
  int BX = blockIdx.x, t = threadIdx.x;
  int w = t >> 6, lane = t & 63, quad = lane >> 4, l15 = lane & 15;
  const f4v zf = (f4v){0.f,0.f,0.f,0.f};
  __shared__ float binS[256];
  __shared__ float cfs[224];
  __shared__ float hm[256];
  __shared__ float xr6[32], xi6[32], x6[32];

  if(BX < 64){
    // ---------------- k3a ----------------
    int kb = BX;
    f4v acc[2][4];
    #pragma unroll
    for(int mt=0;mt<2;mt++)
      #pragma unroll
      for(int nt=0;nt<4;nt++) acc[mt][nt] = zf;
    #pragma unroll
    for(int ks=0;ks<8;ks++){
      long long k = kb*256 + ks*32 + quad*8;
      s8v aF[2], bF[4];
      #pragma unroll
      for(int mt=0;mt<2;mt++)
        aF[mt] = *(const s8v*)(xbf + (long long)(mt*16 + l15)*16384 + k);
      #pragma unroll
      for(int nt=0;nt<4;nt++)
        bF[nt] = *(const s8v*)(W1Tg + (long long)(w*64 + nt*16 + l15)*16384 + k);
      #pragma unroll
      for(int mt=0;mt<2;mt++)
        #pragma unroll
        for(int nt=0;nt<4;nt++)
          acc[mt][nt] = MFMA_BF16(aF[mt], bF[nt], acc[mt][nt]);
    }
    float* po = psum + (long long)kb*8192;
    #pragma unroll
    for(int mt=0;mt<2;mt++)
      #pragma unroll
      for(int nt=0;nt<4;nt++)
        #pragma unroll
        for(int r=0;r<4;r++)
          po[(mt*16 + quad*4 + r)*256 + w*64 + nt*16 + l15] = acc[mt][nt][r];
    return;
  }
  if(BX < 1088){
    // ---------------- k5a (magnitude, computed once) ----------------
    int bx = BX - 64;
    int e = bx >> 7, inner = bx & 127;
    int b = inner >> 2, half = (inner >> 1) & 1, kh = inner & 1;
    int row0 = b*512 + half*128;
    binS[t] = ldg_(b_in, e*256+t, bf);
    s8v xrF[2], xiF[2];
    #pragma unroll
    for(int nt=0;nt<2;nt++){
      long long row = row0 + w*32 + nt*16 + l15;
      xrF[nt] = *(const s8v*)(Xr + row*32 + quad*8);
      xiF[nt] = *(const s8v*)(Xi + row*32 + quad*8);
    }
    __syncthreads();
    u16* Ho = hmagG + (long long)((e<<6)|(b<<1)|half)*32768;
    #pragma unroll
    for(int kcl=0;kcl<2;kcl++){
      int k0 = (kh*2+kcl)*64;
      #pragma unroll
      for(int ct=0;ct<4;ct++){
        s8v wfr = *(const s8v*)(WinTg + ((long long)e*256 + k0 + ct*16 + l15)*32 + quad*8);
        #pragma unroll
        for(int nt=0;nt<2;nt++){
          f4v hr = MFMA_BF16(wfr, xrF[nt], zf);
          f4v hi = MFMA_BF16(wfr, xiF[nt], zf);
          int rowg = row0 + w*32 + nt*16 + l15;
          bool bin0 = ((rowg & 511) == 0);
          ushort4 pk;
          int cb4 = k0 + ct*16 + quad*4;
          float h0 = hr[0] + (bin0 ? 512.f*binS[cb4+0] : 0.f);
          float h1 = hr[1] + (bin0 ? 512.f*binS[cb4+1] : 0.f);
          float h2 = hr[2] + (bin0 ? 512.f*binS[cb4+2] : 0.f);
          float h3 = hr[3] + (bin0 ? 512.f*binS[cb4+3] : 0.f);
          pk.x = f2bf_fast(FSQRT(h0*h0 + hi[0]*hi[0]));
          pk.y = f2bf_fast(FSQRT(h1*h1 + hi[1]*hi[1]));
          pk.z = f2bf_fast(FSQRT(h2*h2 + hi[2]*hi[2]));
          pk.w = f2bf_fast(FSQRT(h3*h3 + hi[3]*hi[3]));
          *(ushort4*)&Ho[(w*32 + nt*16 + l15)*256 + cb4] = pk;
        }
      }
    }
    return;
  }
  if(BX < 1120){
    // ---------------- h1 = relu(cf @ Wf1 + bf1) ----------------
    int b = BX - 1088;
    if(t < 224) cfs[t] = cf[(long long)b*224 + t];
    __syncthreads();
    float a1 = ldg_(bf1, t, bf);
    const u16* Wp_ = gw + GWF1 + t;
    #pragma unroll 16
    for(int k=0;k<224;k++) a1 += cfs[k]*bf2f(Wp_[k*256]);
    h1f[b*256+t] = fmaxf(a1, 0.f);
    return;
  }
  // ---------------- contrib: bin-256 row, u256 * a^255 (no (1-a)) --------
  {
    int bx = BX - 1120;
    int e = bx >> 5, b = bx & 31, j = t;
    if(j < 32){
      long long o = ((long long)(b*512 + 256))*32 + j;
      xr6[j] = bf2f(Xr[o]);
      xi6[j] = bf2f(Xi[o]);
      x6[j]  = bf2f(xbf[o]);
    }
    __syncthreads();
    float sr=0.f, si=0.f, hx=0.f;
    if(bf){
      const u16* Wn = (const u16*)Win + (long long)e*8192 + j;
      #pragma unroll 8
      for(int d=0; d<32; d++){
        float wv = bf2f(Wn[d*256]);
        sr += xr6[d]*wv; si += xi6[d]*wv; hx += x6[d]*wv;
      }
    } else {
      const float* Wn = (const float*)Win + (long long)e*8192 + j;
      #pragma unroll 8
      for(int d=0; d<32; d++){
        float wv = Wn[d*256];
        sr += xr6[d]*wv; si += xi6[d]*wv; hx += x6[d]*wv;
      }
    }
    hm[j] = FSQRT(sr*sr + si*si);
    __syncthreads();
    float f = 0.f;
    if(bf){
      const u16* Wf = (const u16*)Wfft + (long long)e*65536 + j;
      #pragma unroll 8
      for(int k=0;k<256;k++) f += hm[k]*bf2f(Wf[(long long)k*256]);
    } else {
      const float* Wf = (const float*)Wfft + (long long)e*65536 + j;
      #pragma unroll 8
      for(int k=0;k<256;k++) f += hm[k]*Wf[(long long)k*256];
    }
    float a = 1.f/(1.f+__expf(-ldg_(a_logit, e*256+j, bf)));
    a = fminf(fmaxf(a, 1e-12f), 0.99999988f);
    float l2a = FLOG2(a);
    float u = fmaxf(hx + f + ldg_(b_in,e*256+j,bf) + ldg_(b_fft,e*256+j,bf), 0.f);
    contrib[(e*32+b)*256 + j] = u * FEXP2(l2a * 255.f);   // a^(511-256)
  }
}

// ---------------------------------------------------------------------------
// KS3 (fused stage 3): [0,32) kgate_b (inline psum->hs reduce) -> wgt;
// [32,1056) k5b GEMM+decay epilogue -> sp; [1056,1153) zero yacc+done
// (for k6's atomic accumulate). grid 1153.
// ---------------------------------------------------------------------------
__global__ __launch_bounds__(256) void ks3(const void* __restrict__ ln_g,
    const float* __restrict__ psum, const float* __restrict__ h1f,
    const u16* __restrict__ gw,
    const void* __restrict__ b1, const void* __restrict__ bf2,
    const void* __restrict__ ln_b, const void* __restrict__ bp,
    const void* __restrict__ b2, const void* __restrict__ bg,
    const void* __restrict__ log_temp,
    const u16* __restrict__ xbf, const u16* __restrict__ hmagG,
    const u16* __restrict__ WinTg, const u16* __restrict__ WfftTg,
    const void* __restrict__ b_in, const void* __restrict__ b_fft,
    const void* __restrict__ a_logit,
    float* __restrict__ wgt, float* __restrict__ sp,
    float* __restrict__ yacc, int* __restrict__ done){
  const bool bf = bfflag(ln_g);
  int BX = blockIdx.x, t = threadIdx.x;
  __shared__ __align__(16) u16 BsT[128][72];
  __shared__ float biasS[128], l2aS[128], aS[128];
  __shared__ float hsL[256], h1L[256], latL[256], efL[64], prL[64];
  __shared__ float red[4][64];
  __shared__ float d2part[16][16], d2s[16], lgpart[32][8];

  if(BX >= 1056){
    // ---------------- zero yacc (98304 f32) + done (24 ints) ----------------
    int idx = (BX-1056)*256 + t;
    if(idx < 24576) *(float4*)(yacc + idx*4) = (float4){0.f,0.f,0.f,0.f};
    if(BX == 1056 && t < 32) done[t] = 0;
    return;
  }
  if(BX < 32){
    // ---------------- kgate_b (inline hs reduce) ----------------
    int b = BX;
    {
      float s0=0.f, s1=0.f, s2=0.f, s3=0.f;
      #pragma unroll
      for(int kb=0;kb<64;kb+=4){
        s0 += psum[(long long)(kb+0)*8192 + b*256 + t];
        s1 += psum[(long long)(kb+1)*8192 + b*256 + t];
        s2 += psum[(long long)(kb+2)*8192 + b*256 + t];
        s3 += psum[(long long)(kb+3)*8192 + b*256 + t];
      }
      hsL[t] = fmaxf((s0+s1)+(s2+s3) + ldg_(b1,t,bf), 0.f);
    }
    h1L[t] = h1f[b*256+t];
    __syncthreads();                              // S1
    {
      float a = ldg_(b2, t, bf);
      const u16* W2p = gw + GW2 + t;
      #pragma unroll 16
      for(int k=0;k<256;k++) a += hsL[k]*bf2f(W2p[k*256]);
      latL[t] = a;
    }
    {
      int p = t>>6, j = t&63;
      float acc = 0.f;
      const u16* Wf2p = gw + GWF2 + p*64*64 + j;
      #pragma unroll 16
      for(int i=0;i<64;i++) acc += h1L[p*64+i]*bf2f(Wf2p[i*64]);
      red[p][j] = acc;
    }
    __syncthreads();                              // S2
    if(t < 64){
      float a2 = red[0][t]+red[1][t]+red[2][t]+red[3][t] + ldg_(bf2,t,bf);
      float sm=a2, sq=a2*a2;
      #pragma unroll
      for(int o=32;o>0;o>>=1){ sm += __shfl_xor(sm,o); sq += __shfl_xor(sq,o); }
      float mu  = sm*(1.f/64.f);
      float var = sq*(1.f/64.f) - mu*mu;          // ddof=0
      efL[t] = (a2-mu)*rsqrtf(fmaxf(var,0.f)+1e-5f)*ldg_(ln_g,t,bf) + ldg_(ln_b,t,bf);
      float p_acc = ldg_(bp, t, bf);
      const u16* Wpp = gw + GWP + t;
      #pragma unroll 16
      for(int k=0;k<64;k++) p_acc += efL[k]*bf2f(Wpp[k*64]);
      prL[t] = p_acc;
    }
    {
      int part = t>>3, e = t&7;
      float gp = 0.f;
      const u16* Wgp = gw + GWG + e;
      #pragma unroll
      for(int i=0;i<8;i++){
        int k = part*8 + i;
        gp += latL[k]*bf2f(Wgp[k*8]);
      }
      lgpart[part][e] = gp;
    }
    __syncthreads();                              // S3
    {
      int p = t>>4, q4 = t&15;
      float dd = 0.f;
      #pragma unroll
      for(int i=0;i<4;i++){
        int d = q4*4 + i;
        float df = prL[d] - bf2f(gw[GPROT + p*64 + d]);
        dd += df*df;
      }
      d2part[p][q4] = dd;
    }
    __syncthreads();                              // S4
    if(t < 16){
      float s = 0.f;
      #pragma unroll
      for(int i=0;i<16;i++) s += d2part[t][i];
      d2s[t] = s;
    }
    __syncthreads();                              // S5
    if(t < 8){
      float g = ldg_(bg, t, bf);
      #pragma unroll
      for(int p=0;p<32;p++) g += lgpart[p][t];
      float d2pe = fminf(d2s[2*t], d2s[2*t+1]);   // NPROT/E = 2
      float temp = fminf(fmaxf(__expf(ldg_(log_temp,0,bf)), 0.1f), 10.f);
      float v = (g - d2pe) / temp;
      float m = v;
      m = fmaxf(m, __shfl_xor(m,1));
      m = fmaxf(m, __shfl_xor(m,2));
      m = fmaxf(m, __shfl_xor(m,4));
      float ex = __expf(v-m);
      float sum = ex;
      sum += __shfl_xor(sum,1);
      sum += __shfl_xor(sum,2);
      sum += __shfl_xor(sum,4);
      wgt[b*8+t] = ex/sum;
    }
    return;
  }
  // ---------------- k5b (f GEMM + decay epilogue) ----------------
  {
    int bx = BX - 32;
    int e = bx >> 7, inner = bx & 127;
    int b = inner >> 2, half = (inner >> 1) & 1, cb = inner & 1;
    int row0 = b*512 + half*128;
    int col0 = cb*128;
    int w = t >> 6, lane = t & 63, quad = lane >> 4, l15 = lane & 15;

    if(t < 128){
      int c = col0 + t;
      biasS[t] = ldg_(b_in, e*256+c, bf) + ldg_(b_fft, e*256+c, bf);
      float a = 1.f/(1.f+__expf(-ldg_(a_logit, e*256+c, bf)));
      a = fminf(fmaxf(a, 1e-12f), 0.99999988f);
      aS[t] = a;
      l2aS[t] = FLOG2(a);
    }
    const u16* Ab = hmagG + (long long)((e<<6)|(b<<1)|half)*32768;
    const f4v zf = (f4v){0.f,0.f,0.f,0.f};
    f4v acc[2][8];
    #pragma unroll
    for(int mt=0;mt<2;mt++)
      #pragma unroll
      for(int nt=0;nt<8;nt++) acc[mt][nt] = zf;

    for(int kc=0;kc<4;kc++){
      int k0 = kc*64;
      __syncthreads();
      #pragma unroll
      for(int q=0;q<4;q++){
        int G = q*256 + t;
        int c = G >> 3, k8 = (G & 7)*8;
        *(s8v*)&BsT[c][k8] = *(const s8v*)(WfftTg + ((long long)e*256 + col0 + c)*256 + k0 + k8);
      }
      __syncthreads();
      #pragma unroll
      for(int ks=0;ks<2;ks++){
        int kb = ks*32 + quad*8;
        s8v aF0 = *(const s8v*)(Ab + (w*32 + l15)*256 + k0 + kb);
        s8v aF1 = *(const s8v*)(Ab + (w*32 + 16 + l15)*256 + k0 + kb);
        #pragma unroll
        for(int nt=0;nt<8;nt++){
          s8v bF = *(const s8v*)&BsT[nt*16 + l15][kb];
          acc[0][nt] = MFMA_BF16(aF0, bF, acc[0][nt]);
          acc[1][nt] = MFMA_BF16(aF1, bF, acc[1][nt]);
        }
      }
    }
    // epilogue: apply f to original rows l and mirror rows 512-l
    s8v xF[2], xFm[2];
    #pragma unroll
    for(int mt=0;mt<2;mt++){
      long long rowO = (long long)row0 + w*32 + mt*16 + l15;
      xF[mt] = *(const s8v*)(xbf + rowO*32 + quad*8);
      int lin = half*128 + w*32 + mt*16 + l15;
      int lm  = (512 - lin) & 511;
      xFm[mt] = *(const s8v*)(xbf + ((long long)b*512 + lm)*32 + quad*8);
    }
    int l0base = half*128 + w*32 + quad*4;
    float mz = (l0base == 0) ? 0.f : 1.f;
    const f4v zf2 = (f4v){0.f,0.f,0.f,0.f};
    float part[8];
    #pragma unroll
    for(int nt=0;nt<8;nt++){
      s8v wfh = *(const s8v*)(WinTg + ((long long)e*256 + col0 + nt*16 + l15)*32 + quad*8);
      f4v hv0 = MFMA_BF16(xF[0],  wfh, zf2);
      f4v hv1 = MFMA_BF16(xF[1],  wfh, zf2);
      f4v hm0 = MFMA_BF16(xFm[0], wfh, zf2);
      f4v hm1 = MFMA_BF16(xFm[1], wfh, zf2);
      int cl = nt*16 + l15;
      float l2a = l2aS[cl], bias = biasS[cl], av = aS[cl];
      float inv_a = FEXP2(-l2a);
      float cO0 = FEXP2(l2a * (float)(511 - l0base));
      float cO1 = FEXP2(l2a * (float)(495 - l0base));
      float cM0 = FEXP2(l2a * (float)(l0base - 1));
      float cM1 = FEXP2(l2a * (float)(l0base + 15));
      float sum = 0.f;
      #pragma unroll
      for(int r=0;r<4;r++){
        float u0 = fmaxf(acc[0][nt][r] + hv0[r] + bias, 0.f);
        sum += u0 * cO0;
        float u1 = fmaxf(acc[1][nt][r] + hv1[r] + bias, 0.f);
        sum += u1 * cO1;
        float m0 = fmaxf(acc[0][nt][r] + hm0[r] + bias, 0.f);
        float w0 = m0 * cM0;
        if(r == 0) w0 *= mz;
        sum += w0;
        float m1 = fmaxf(acc[1][nt][r] + hm1[r] + bias, 0.f);
        sum += m1 * cM1;
        cO0 *= inv_a; cO1 *= inv_a; cM0 *= av; cM1 *= av;
      }
      part[nt] = sum;
    }
    __syncthreads();
    float (*redS)[132] = (float(*)[132])BsT;
    #pragma unroll
    for(int nt=0;nt<8;nt++)
      redS[w*4 + quad][nt*16 + l15] = part[nt];
    __syncthreads();
    if(t < 128){
      float tot = 0.f;
      #pragma unroll
      for(int i=0;i<16;i++) tot += redS[i][t];
      sp[e*16384 + (b*2 + half)*256 + col0 + t] = tot;
    }
  }
}

// ---------------------------------------------------------------------------
// K6 v4 (fused head, e-parallel + last-block-converts): each block builds
// its expert's ss[32][256] tile in LDS, runs 32 MFMA vs WheadTg[e], and
// atomically accumulates wgt[b,e]*(acc + b_head) into yacc. The 8th
// arriving block per column-tile (done[nb]) converts yacc -> out.
// grid (24,8).
// ---------------------------------------------------------------------------
__global__ __launch_bounds__(256) void k6_mfma(const void* __restrict__ ln_g,
    const float* __restrict__ sp, const float* __restrict__ contrib,
    const float* __restrict__ wgt, const void* __restrict__ a_logit,
    const u16* __restrict__ WheadTg, const void* __restrict__ b_head,
    float* __restrict__ yacc, int* __restrict__ done,
    void* __restrict__ out){
  const bool bf = bfflag(ln_g);
  int nb = blockIdx.x, e = blockIdx.y;
  int t = threadIdx.x;
  int w = t >> 6, lane = t & 63, quad = lane >> 4, l15 = lane & 15;
  __shared__ __align__(16) u16 ssS[32][264];   // row stride 528B (16B-aligned)
  __shared__ float wgtS[256];
  __shared__ int sdone;
  wgtS[t] = wgt[t];
  // build ss tile: thread t owns column k=t across the 32 batch rows
  {
    float a = 1.f/(1.f+__expf(-ldg_(a_logit, e*256+t, bf)));
    a = fminf(fmaxf(a, 1e-12f), 0.99999988f);
    float oma = 1.f - a;
    const float* sp0 = sp + e*16384 + t;
    const float* cb  = contrib + e*8192 + t;
    #pragma unroll
    for(int q=0;q<32;q++){
      float v = oma*(sp0[q*512] + sp0[q*512+256] + cb[q*256]);
      ssS[q][t] = f2bf(v);
    }
  }
  __syncthreads();
  const f4v zf = (f4v){0.f,0.f,0.f,0.f};
  f4v acc[2][2];
  #pragma unroll
  for(int mt=0;mt<2;mt++)
    #pragma unroll
    for(int nt=0;nt<2;nt++) acc[mt][nt] = zf;
  #pragma unroll
  for(int ks=0;ks<8;ks++){
    int k = ks*32 + quad*8;
    s8v aF0 = *(const s8v*)&ssS[l15][k];
    s8v aF1 = *(const s8v*)&ssS[16 + l15][k];
    s8v bF[2];
    #pragma unroll
    for(int nt=0;nt<2;nt++)
      bF[nt] = *(const s8v*)(WheadTg + ((long long)e*3072 + nb*128 + w*32 + nt*16 + l15)*256 + k);
    acc[0][0] = MFMA_BF16(aF0, bF[0], acc[0][0]);
    acc[0][1] = MFMA_BF16(aF0, bF[1], acc[0][1]);
    acc[1][0] = MFMA_BF16(aF1, bF[0], acc[1][0]);
    acc[1][1] = MFMA_BF16(aF1, bF[1], acc[1][1]);
  }
  // wgt-scaled atomic accumulate (+ b_head term)
  #pragma unroll
  for(int nt=0;nt<2;nt++){
    int col = nb*128 + w*32 + nt*16 + l15;
    float bh = ldg_(b_head, (long long)e*3072 + col, bf);
    #pragma unroll
    for(int mt=0;mt<2;mt++)
      #pragma unroll
      for(int r=0;r<4;r++){
        int b = mt*16 + quad*4 + r;
        atomicAdd(&yacc[b*3072 + col], wgtS[b*8+e]*(acc[mt][nt][r] + bh));
      }
  }
  __syncthreads();   // all this block's atomics drained (vmcnt(0) before barrier)
  if(t == 0){
    __threadfence();
    sdone = (atomicAdd(&done[nb], 1) == 7);
  }
  __syncthreads();
  if(sdone){
    // last block for this column tile: convert yacc -> out (coherent reads)
    #pragma unroll
    for(int q=0;q<16;q++){
      int idx = q*256 + t;            // 0..4095 = 32 b x 128 cols
      int b = idx >> 7, c = idx & 127;
      long long o = (long long)b*3072 + nb*128 + c;
      float v = atomicAdd(&yacc[o], 0.f);
      if(bf) ((u16*)out)[o] = f2bf(v);
      else   ((float*)out)[o] = v;
    }
  }
}

// ---------------------------------------------------------------------------
extern "C" void kernel_launch(void* const* d_in, const int* in_sizes, int n_in,
                              void* d_out, int out_size, void* d_ws, size_t ws_size,
                              hipStream_t stream){
  const void* x       = d_in[0];
  const void* prot    = d_in[1];
  const void* Wp      = d_in[2];
  const void* bp      = d_in[3];
  const void* Wf1     = d_in[4];
  const void* bf1     = d_in[5];
  const void* Wf2     = d_in[6];
  const void* bf2     = d_in[7];
  const void* ln_g    = d_in[8];
  const void* ln_b    = d_in[9];
  const void* W1      = d_in[10];
  const void* b1      = d_in[11];
  const void* W2      = d_in[12];
  const void* b2      = d_in[13];
  const void* Wg      = d_in[14];
  const void* bg      = d_in[15];
  const void* log_temp= d_in[16];
  const void* Win     = d_in[17];
  const void* b_in    = d_in[18];
  const void* Wfft    = d_in[19];
  const void* b_fft   = d_in[20];
  const void* a_logit = d_in[21];
  const void* Whead   = d_in[22];
  const void* b_head  = d_in[23];

  // ws layout: ~62 MB
  float* ws      = (float*)d_ws;
  float* cf      = ws;                       // 7168
  float* wgt     = cf + 7168;                // 256
  float* sp      = wgt + 256;                // 131072
  float* h1f     = sp + 131072;              // 8192
  float* contrib = h1f + 8192;               // 65536 (8 x 32 x 256 fp32)
  float* psum    = contrib + 65536;          // 524288
  float* yacc    = psum + 524288;            // 98304 (32 x 3072 fp32)
  int*   done    = (int*)(yacc + 98304);     // 32 ints (24 used)
  u16*   Xr      = (u16*)(done + 32);        // 524288 bf16 (bins 0..256 used)
  u16*   Xi      = Xr + 524288;              // 524288
  u16*   xbf     = Xi + 524288;              // 524288
  u16*   WinTg   = xbf + 524288;             // 65536
  u16*   WfftTg  = WinTg + 65536;            // 524288
  u16*   W1Tg    = WfftTg + 524288;          // 4194304
  u16*   WheadTg = W1Tg + 4194304;           // 6291456
  u16*   gw      = WheadTg + 6291456;        // 146432
  u16*   hmagG   = gw + 146432;              // 16777216 (8*64*128*256 bf16)

  ks1 <<<dim3(4623), dim3(256), 0, stream>>>(ln_g, x, Win, Wfft, W1, Whead,
                                             Wf1, W2, Wf2, Wp, prot, Wg,
                                             xbf, WinTg, WfftTg, W1Tg, WheadTg, gw,
                                             Xr, Xi, cf);
  ks2 <<<dim3(1376), dim3(256), 0, stream>>>(ln_g, xbf, Xr, Xi, WinTg, W1Tg,
                                             gw, cf, bf1, b_in, b_fft, a_logit,
                                             Win, Wfft,
                                             psum, hmagG, h1f, contrib);
  ks3 <<<dim3(1153), dim3(256), 0, stream>>>(ln_g, psum, h1f, gw,
                                             b1, bf2, ln_b, bp, b2, bg, log_temp,
                                             xbf, hmagG, WinTg, WfftTg,
                                             b_in, b_fft, a_logit,
                                             wgt, sp, yacc, done);
  k6_mfma <<<dim3(24,8), dim3(256), 0, stream>>>(ln_g, sp, contrib, wgt, a_logit,
                                                 WheadTg, b_head, yacc, done, d_out);
}

// Round 10
// 195.551 us; speedup vs baseline: 1.0516x; 1.0516x over previous
//
#include <hip/hip_runtime.h>
#include <hip/hip_bf16.h>

// Dims (fixed): B=32, L=512, D=32, H=256, E=8, PLEN*O=3072, LAT=256, PD=64, NPROT=16

typedef __hip_bfloat16 bf16;
typedef unsigned short u16;
typedef __attribute__((ext_vector_type(8))) short s8v;   // 8 bf16 MFMA A/B frag
typedef __attribute__((ext_vector_type(4))) float f4v;   // MFMA C/D frag

#define MFMA_BF16(a,b,c) __builtin_amdgcn_mfma_f32_16x16x32_bf16(a,b,c,0,0,0)

#if __has_builtin(__builtin_amdgcn_sqrtf)
#define FSQRT(x) __builtin_amdgcn_sqrtf(x)
#else
#define FSQRT(x) sqrtf(x)
#endif
#if __has_builtin(__builtin_amdgcn_exp2f)
#define FEXP2(x) __builtin_amdgcn_exp2f(x)
#else
#define FEXP2(x) exp2f(x)
#endif
#if __has_builtin(__builtin_amdgcn_logf)
#define FLOG2(x) __builtin_amdgcn_logf(x)
#else
#define FLOG2(x) log2f(x)
#endif

// gw blob u16 offsets
#define GWF1 0
#define GW2  57344
#define GWF2 122880
#define GWP  139264
#define GPROT 143360
#define GWG  144384
// total 146432 u16

__device__ __forceinline__ float bf2f(u16 u){
  union{ unsigned u32; float f; } w; w.u32 = ((unsigned)u) << 16; return w.f;
}
__device__ __forceinline__ u16 f2bf(float f){
  bf16 h = __float2bfloat16(f);
  union{ bf16 b; u16 u; } w; w.b = h; return w.u;
}
__device__ __forceinline__ u16 f2bf_fast(float f){
  union{ float f; unsigned u; } v; v.f = f;
  unsigned r = v.u + 0x7FFFu + ((v.u >> 16) & 1u);
  return (u16)(r >> 16);
}
__device__ __forceinline__ float ldg_(const void* p, long long i, bool bf){
  float r;
  if(bf) r = bf2f(((const u16*)p)[i]);
  else   r = ((const float*)p)[i];
  return r;
}
__device__ __forceinline__ bool bfflag(const void* ln_g){
  return ((const u16*)ln_g)[0] == 0x3F80;
}

// ---------------------------------------------------------------------------
// KS1 (fused input stage): [0,1024) k1_fft; [1024,4111) kt_all;
// [4111,4623) kx_cvt. All parts read only kernel inputs. grid 4623.
// Xr/Xi stored only for bins 0..256 (rows 257..511 are never read:
// k5a uses bins 0..255, contrib uses bin 256 — Hermitian symmetry).
// ---------------------------------------------------------------------------
__global__ __launch_bounds__(256) void ks1(const void* __restrict__ ln_g,
    const void* __restrict__ x,
    const void* __restrict__ Win, const void* __restrict__ Wfft,
    const void* __restrict__ W1, const void* __restrict__ Whead,
    const void* __restrict__ Wf1, const void* __restrict__ W2,
    const void* __restrict__ Wf2, const void* __restrict__ Wp,
    const void* __restrict__ prot, const void* __restrict__ Wg,
    u16* __restrict__ xbf,
    u16* __restrict__ WinTg, u16* __restrict__ WfftTg,
    u16* __restrict__ W1Tg, u16* __restrict__ WheadTg,
    u16* __restrict__ gw,
    u16* __restrict__ Xr, u16* __restrict__ Xi, float* __restrict__ cf){
  const bool bf = bfflag(ln_g);
  __shared__ float xs[512], re[512], im[512];
  __shared__ float twr[256], twi[256];
  __shared__ float r0s[4], r1s[4], r2s[4], r3s[4];
  __shared__ u16 tile[64][72];
  int BX = blockIdx.x, t = threadIdx.x;

  if(BX < 1024){
    // ---------------- k1_fft ----------------
    int b = BX >> 5, d = BX & 31;
    {
      float rev = -(float)t * (1.f/512.f);
#if __has_builtin(__builtin_amdgcn_cosf) && __has_builtin(__builtin_amdgcn_sinf)
      twr[t] = __builtin_amdgcn_cosf(rev);
      twi[t] = __builtin_amdgcn_sinf(rev);
#else
      float ang = rev * 6.283185307179586f;
      twr[t] = cosf(ang); twi[t] = sinf(ang);
#endif
    }
    for(int i=t;i<512;i+=256){
      float v = ldg_(x, (long long)(b*512+i)*32 + d, bf);
      xs[i] = v;
      re[__brev((unsigned)i) >> 23] = v;
      im[i] = 0.f;
    }
    __syncthreads();
    float s=0.f, s2=0.f, mn=3.0e38f, mx=-3.0e38f;
    for(int i=t;i<512;i+=256){ float v=xs[i]; s+=v; s2+=v*v; mn=fminf(mn,v); mx=fmaxf(mx,v); }
    #pragma unroll
    for(int o=32;o>0;o>>=1){
      s  += __shfl_down(s,o);  s2 += __shfl_down(s2,o);
      mn = fminf(mn,__shfl_down(mn,o)); mx = fmaxf(mx,__shfl_down(mx,o));
    }
    int wv = t>>6, ln = t&63;
    if(ln==0){ r0s[wv]=s; r1s[wv]=s2; r2s[wv]=mn; r3s[wv]=mx; }
    __syncthreads();
    if(t==0){
      float S =r0s[0]+r0s[1]+r0s[2]+r0s[3];
      float S2=r1s[0]+r1s[1]+r1s[2]+r1s[3];
      float MN=fminf(fminf(r2s[0],r2s[1]),fminf(r2s[2],r2s[3]));
      float MX=fmaxf(fmaxf(r3s[0],r3s[1]),fmaxf(r3s[2],r3s[3]));
      float mean = S*(1.f/512.f);
      float var  = (S2 - S*S*(1.f/512.f))*(1.f/511.f);   // ddof=1
      float* c = cf + b*224;
      c[d]      = mean;
      c[32+d]   = sqrtf(fmaxf(var,0.f));
      c[64+d]   = MN;
      c[96+d]   = MX;
      float dv = xs[511]-xs[0];
      c[128+d]  = dv*(1.f/511.f);
      c[160+d]  = dv*(1.f/512.f);
    }
    for(int st=1; st<=9; ++st){
      __syncthreads();
      int m = 1<<st, half = m>>1;
      int grp = t >> (st-1);
      int k   = t & (half-1);
      int i1 = grp*m + k, i2 = i1 + half;
      int ti_ = k << (9-st);
      float cs = twr[ti_], sn = twi[ti_];
      float ar=re[i1], ai=im[i1], br=re[i2], bi=im[i2];
      float tr = cs*br - sn*bi;
      float ti = cs*bi + sn*br;
      re[i1]=ar+tr; im[i1]=ai+ti;
      re[i2]=ar-tr; im[i2]=ai-ti;
    }
    __syncthreads();
    float ms=0.f;
    for(int i=t;i<512;i+=256){
      float rr=re[i], ii=im[i];
      if(i <= 256){
        long long o = (long long)(b*512+i)*32 + d;
        Xr[o]=f2bf(rr); Xi[o]=f2bf(ii);
      }
      ms += FSQRT(rr*rr+ii*ii);
    }
    #pragma unroll
    for(int o=32;o>0;o>>=1) ms += __shfl_down(ms,o);
    if(ln==0) r0s[wv]=ms;
    __syncthreads();
    if(t==0) cf[b*224 + 192 + d] = (r0s[0]+r0s[1]+r0s[2]+r0s[3])*(1.f/512.f);
    return;
  }
  if(BX < 4111){
    // ---------------- kt_all ----------------
    int bx = BX - 1024;
    if(bx < 256){
      int i = bx*256 + t;
      int e = i >> 13, r = i & 8191;
      int c = r >> 5, d = r & 31;
      WinTg[i] = f2bf(ldg_(Win, (long long)e*8192 + d*256 + c, bf));
      return;
    }
    if(bx < 384){
      int idx = bx - 256;
      int e = idx >> 4, tl = idx & 15, kb = tl >> 2, cb = tl & 3;
      if(bf){
        for(int q=0;q<16;q++){
          int G = q*256 + t; int ki = G >> 6, ci = G & 63;
          tile[ci][ki] = ((const u16*)Wfft)[(long long)e*65536 + (long long)(kb*64+ki)*256 + cb*64+ci];
        }
      } else {
        for(int q=0;q<16;q++){
          int G = q*256 + t; int ki = G >> 6, ci = G & 63;
          tile[ci][ki] = f2bf(((const float*)Wfft)[(long long)e*65536 + (long long)(kb*64+ki)*256 + cb*64+ci]);
        }
      }
      __syncthreads();
      for(int q=0;q<16;q++){
        int G = q*256 + t; int ci = G >> 6, ki = G & 63;
        WfftTg[(long long)e*65536 + (long long)(cb*64+ci)*256 + kb*64+ki] = tile[ci][ki];
      }
      return;
    }
    if(bx < 1408){
      int idx = bx - 384;
      int kb = idx & 255, nb = idx >> 8;
      if(bf){
        for(int q=0;q<16;q++){
          int G = q*256 + t; int ki = G >> 6, ni = G & 63;
          tile[ni][ki] = ((const u16*)W1)[(long long)(kb*64+ki)*256 + nb*64+ni];
        }
      } else {
        for(int q=0;q<16;q++){
          int G = q*256 + t; int ki = G >> 6, ni = G & 63;
          tile[ni][ki] = f2bf(((const float*)W1)[(long long)(kb*64+ki)*256 + nb*64+ni]);
        }
      }
      __syncthreads();
      for(int q=0;q<16;q++){
        int G = q*256 + t; int ni = G >> 6, ki = G & 63;
        W1Tg[(long long)(nb*64+ni)*16384 + kb*64+ki] = tile[ni][ki];
      }
      return;
    }
    if(bx < 2944){
      int idx = bx - 1408;
      int e = idx / 192, rem = idx % 192;
      int kb = rem / 48, nb = rem % 48;
      if(bf){
        for(int q=0;q<16;q++){
          int G = q*256 + t; int ki = G >> 6, ni = G & 63;
          tile[ni][ki] = ((const u16*)Whead)[(long long)e*786432 + (long long)(kb*64+ki)*3072 + nb*64+ni];
        }
      } else {
        for(int q=0;q<16;q++){
          int G = q*256 + t; int ki = G >> 6, ni = G & 63;
          tile[ni][ki] = f2bf(((const float*)Whead)[(long long)e*786432 + (long long)(kb*64+ki)*3072 + nb*64+ni]);
        }
      }
      __syncthreads();
      for(int q=0;q<16;q++){
        int G = q*256 + t; int ni = G >> 6, ki = G & 63;
        WheadTg[(long long)e*786432 + (long long)(nb*64+ni)*256 + kb*64+ki] = tile[ni][ki];
      }
      return;
    }
    // gw blob copies
    {
      int c = bx - 2944;
      const void* src; int dstbase, blkoff;
      if(c < 56)      { src=Wf1;  dstbase=GWF1;  blkoff=c; }
      else if(c <120) { src=W2;   dstbase=GW2;   blkoff=c-56; }
      else if(c <136) { src=Wf2;  dstbase=GWF2;  blkoff=c-120; }
      else if(c <140) { src=Wp;   dstbase=GWP;   blkoff=c-136; }
      else if(c <141) { src=prot; dstbase=GPROT; blkoff=0; }
      else            { src=Wg;   dstbase=GWG;   blkoff=c-141; }
      int i = blkoff*1024 + t*4;
      if(bf){
        ushort4 v = *(const ushort4*)((const u16*)src + i);
        *(ushort4*)(gw + dstbase + i) = v;
      } else {
        float4 f = *(const float4*)((const float*)src + i);
        ushort4 v; v.x=f2bf(f.x); v.y=f2bf(f.y); v.z=f2bf(f.z); v.w=f2bf(f.w);
        *(ushort4*)(gw + dstbase + i) = v;
      }
    }
    return;
  }
  // ---------------- kx_cvt ----------------
  {
    int i = ((BX-4111)*256 + t)*4;
    if(bf){
      ushort4 v = *(const ushort4*)((const u16*)x + i);
      *(ushort4*)(xbf+i) = v;
    } else {
      float4 f = *(const float4*)((const float*)x + i);
      ushort4 v; v.x=f2bf(f.x); v.y=f2bf(f.y); v.z=f2bf(f.z); v.w=f2bf(f.w);
      *(ushort4*)(xbf+i) = v;
    }
  }
}

// ---------------------------------------------------------------------------
// KS2 (fused stage 2): [0,64) k3a psum GEMM; [64,1088) k5a magnitude;
// [1088,1120) h1 = relu(cf@Wf1+bf1); [1120,1376) contrib (bin-256 fixup).
// grid 1376.
// ---------------------------------------------------------------------------
__global__ __launch_bounds__(256) void ks2(const void* __restrict__ ln_g,
    const u16* __restrict__ xbf, const u16* __restrict__ Xr, const u16* __restrict__ Xi,
    const u16* __restrict__ WinTg, const u16* __restrict__ W1Tg,
    const u16* __restrict__ gw, const float* __restrict__ cf,
    const void* __restrict__ bf1, const void* __restrict__ b_in,
    const void* __restrict__ b_fft, const void* __restrict__ a_logit,
    const void* __restrict__ Win, const void* __restrict__ Wfft,
    float* __restrict__ psum, u16* __restrict__ hmagG,
    float* __restrict__ h1f, float* __restrict__ contrib){
  const bool bf = bfflag(ln_g);
  int BX = blockIdx.x, t = threadIdx.x;
  int w = t >> 6, lane = t & 63, quad = lane >> 4, l15 = lane & 15;
  const f4v zf = (f4v){0.f,0.f,0.f,0.f};
  __shared__ float binS[256];
  __shared__ float cfs[224];
  __shared__ float hm[256];
  __shared__ float xr6[32], xi6[32], x6[32];

  if(BX < 64){
    // ---------------- k3a ----------------
    int kb = BX;
    f4v acc[2][4];
    #pragma unroll
    for(int mt=0;mt<2;mt++)
      #pragma unroll
      for(int nt=0;nt<4;nt++) acc[mt][nt] = zf;
    #pragma unroll
    for(int ks=0;ks<8;ks++){
      long long k = kb*256 + ks*32 + quad*8;
      s8v aF[2], bF[4];
      #pragma unroll
      for(int mt=0;mt<2;mt++)
        aF[mt] = *(const s8v*)(xbf + (long long)(mt*16 + l15)*16384 + k);
      #pragma unroll
      for(int nt=0;nt<4;nt++)
        bF[nt] = *(const s8v*)(W1Tg + (long long)(w*64 + nt*16 + l15)*16384 + k);
      #pragma unroll
      for(int mt=0;mt<2;mt++)
        #pragma unroll
        for(int nt=0;nt<4;nt++)
          acc[mt][nt] = MFMA_BF16(aF[mt], bF[nt], acc[mt][nt]);
    }
    float* po = psum + (long long)kb*8192;
    #pragma unroll
    for(int mt=0;mt<2;mt++)
      #pragma unroll
      for(int nt=0;nt<4;nt++)
        #pragma unroll
        for(int r=0;r<4;r++)
          po[(mt*16 + quad*4 + r)*256 + w*64 + nt*16 + l15] = acc[mt][nt][r];
    return;
  }
  if(BX < 1088){
    // ---------------- k5a (magnitude, computed once) ----------------
    int bx = BX - 64;
    int e = bx >> 7, inner = bx & 127;
    int b = inner >> 2, half = (inner >> 1) & 1, kh = inner & 1;
    int row0 = b*512 + half*128;
    binS[t] = ldg_(b_in, e*256+t, bf);
    s8v xrF[2], xiF[2];
    #pragma unroll
    for(int nt=0;nt<2;nt++){
      long long row = row0 + w*32 + nt*16 + l15;
      xrF[nt] = *(const s8v*)(Xr + row*32 + quad*8);
      xiF[nt] = *(const s8v*)(Xi + row*32 + quad*8);
    }
    __syncthreads();
    u16* Ho = hmagG + (long long)((e<<6)|(b<<1)|half)*32768;
    #pragma unroll
    for(int kcl=0;kcl<2;kcl++){
      int k0 = (kh*2+kcl)*64;
      #pragma unroll
      for(int ct=0;ct<4;ct++){
        s8v wfr = *(const s8v*)(WinTg + ((long long)e*256 + k0 + ct*16 + l15)*32 + quad*8);
        #pragma unroll
        for(int nt=0;nt<2;nt++){
          f4v hr = MFMA_BF16(wfr, xrF[nt], zf);
          f4v hi = MFMA_BF16(wfr, xiF[nt], zf);
          int rowg = row0 + w*32 + nt*16 + l15;
          bool bin0 = ((rowg & 511) == 0);
          ushort4 pk;
          int cb4 = k0 + ct*16 + quad*4;
          float h0 = hr[0] + (bin0 ? 512.f*binS[cb4+0] : 0.f);
          float h1 = hr[1] + (bin0 ? 512.f*binS[cb4+1] : 0.f);
          float h2 = hr[2] + (bin0 ? 512.f*binS[cb4+2] : 0.f);
          float h3 = hr[3] + (bin0 ? 512.f*binS[cb4+3] : 0.f);
          pk.x = f2bf_fast(FSQRT(h0*h0 + hi[0]*hi[0]));
          pk.y = f2bf_fast(FSQRT(h1*h1 + hi[1]*hi[1]));
          pk.z = f2bf_fast(FSQRT(h2*h2 + hi[2]*hi[2]));
          pk.w = f2bf_fast(FSQRT(h3*h3 + hi[3]*hi[3]));
          *(ushort4*)&Ho[(w*32 + nt*16 + l15)*256 + cb4] = pk;
        }
      }
    }
    return;
  }
  if(BX < 1120){
    // ---------------- h1 = relu(cf @ Wf1 + bf1) ----------------
    int b = BX - 1088;
    if(t < 224) cfs[t] = cf[(long long)b*224 + t];
    __syncthreads();
    float a1 = ldg_(bf1, t, bf);
    const u16* Wp_ = gw + GWF1 + t;
    #pragma unroll 16
    for(int k=0;k<224;k++) a1 += cfs[k]*bf2f(Wp_[k*256]);
    h1f[b*256+t] = fmaxf(a1, 0.f);
    return;
  }
  // ---------------- contrib: bin-256 row, u256 * a^255 (no (1-a)) --------
  {
    int bx = BX - 1120;
    int e = bx >> 5, b = bx & 31, j = t;
    if(j < 32){
      long long o = ((long long)(b*512 + 256))*32 + j;
      xr6[j] = bf2f(Xr[o]);
      xi6[j] = bf2f(Xi[o]);
      x6[j]  = bf2f(xbf[o]);
    }
    __syncthreads();
    float sr=0.f, si=0.f, hx=0.f;
    if(bf){
      const u16* Wn = (const u16*)Win + (long long)e*8192 + j;
      #pragma unroll 8
      for(int d=0; d<32; d++){
        float wv = bf2f(Wn[d*256]);
        sr += xr6[d]*wv; si += xi6[d]*wv; hx += x6[d]*wv;
      }
    } else {
      const float* Wn = (const float*)Win + (long long)e*8192 + j;
      #pragma unroll 8
      for(int d=0; d<32; d++){
        float wv = Wn[d*256];
        sr += xr6[d]*wv; si += xi6[d]*wv; hx += x6[d]*wv;
      }
    }
    hm[j] = FSQRT(sr*sr + si*si);
    __syncthreads();
    float f = 0.f;
    if(bf){
      const u16* Wf = (const u16*)Wfft + (long long)e*65536 + j;
      #pragma unroll 8
      for(int k=0;k<256;k++) f += hm[k]*bf2f(Wf[(long long)k*256]);
    } else {
      const float* Wf = (const float*)Wfft + (long long)e*65536 + j;
      #pragma unroll 8
      for(int k=0;k<256;k++) f += hm[k]*Wf[(long long)k*256];
    }
    float a = 1.f/(1.f+__expf(-ldg_(a_logit, e*256+j, bf)));
    a = fminf(fmaxf(a, 1e-12f), 0.99999988f);
    float l2a = FLOG2(a);
    float u = fmaxf(hx + f + ldg_(b_in,e*256+j,bf) + ldg_(b_fft,e*256+j,bf), 0.f);
    contrib[(e*32+b)*256 + j] = u * FEXP2(l2a * 255.f);   // a^(511-256)
  }
}

// ---------------------------------------------------------------------------
// KS3 (fused stage 3): [0,32) kgate_b (inline psum->hs reduce) -> wgt;
// [32,1056) k5b GEMM+decay epilogue -> sp. grid 1056.
// ---------------------------------------------------------------------------
__global__ __launch_bounds__(256) void ks3(const void* __restrict__ ln_g,
    const float* __restrict__ psum, const float* __restrict__ h1f,
    const u16* __restrict__ gw,
    const void* __restrict__ b1, const void* __restrict__ bf2,
    const void* __restrict__ ln_b, const void* __restrict__ bp,
    const void* __restrict__ b2, const void* __restrict__ bg,
    const void* __restrict__ log_temp,
    const u16* __restrict__ xbf, const u16* __restrict__ hmagG,
    const u16* __restrict__ WinTg, const u16* __restrict__ WfftTg,
    const void* __restrict__ b_in, const void* __restrict__ b_fft,
    const void* __restrict__ a_logit,
    float* __restrict__ wgt, float* __restrict__ sp){
  const bool bf = bfflag(ln_g);
  int BX = blockIdx.x, t = threadIdx.x;
  __shared__ __align__(16) u16 BsT[128][72];
  __shared__ float biasS[128], l2aS[128], aS[128];
  __shared__ float hsL[256], h1L[256], latL[256], efL[64], prL[64];
  __shared__ float red[4][64];
  __shared__ float d2part[16][16], d2s[16], lgpart[32][8];

  if(BX < 32){
    // ---------------- kgate_b (inline hs reduce) ----------------
    int b = BX;
    {
      float s0=0.f, s1=0.f, s2=0.f, s3=0.f;
      #pragma unroll
      for(int kb=0;kb<64;kb+=4){
        s0 += psum[(long long)(kb+0)*8192 + b*256 + t];
        s1 += psum[(long long)(kb+1)*8192 + b*256 + t];
        s2 += psum[(long long)(kb+2)*8192 + b*256 + t];
        s3 += psum[(long long)(kb+3)*8192 + b*256 + t];
      }
      hsL[t] = fmaxf((s0+s1)+(s2+s3) + ldg_(b1,t,bf), 0.f);
    }
    h1L[t] = h1f[b*256+t];
    __syncthreads();                              // S1
    {
      float a = ldg_(b2, t, bf);
      const u16* W2p = gw + GW2 + t;
      #pragma unroll 16
      for(int k=0;k<256;k++) a += hsL[k]*bf2f(W2p[k*256]);
      latL[t] = a;
    }
    {
      int p = t>>6, j = t&63;
      float acc = 0.f;
      const u16* Wf2p = gw + GWF2 + p*64*64 + j;
      #pragma unroll 16
      for(int i=0;i<64;i++) acc += h1L[p*64+i]*bf2f(Wf2p[i*64]);
      red[p][j] = acc;
    }
    __syncthreads();                              // S2
    if(t < 64){
      float a2 = red[0][t]+red[1][t]+red[2][t]+red[3][t] + ldg_(bf2,t,bf);
      float sm=a2, sq=a2*a2;
      #pragma unroll
      for(int o=32;o>0;o>>=1){ sm += __shfl_xor(sm,o); sq += __shfl_xor(sq,o); }
      float mu  = sm*(1.f/64.f);
      float var = sq*(1.f/64.f) - mu*mu;          // ddof=0
      efL[t] = (a2-mu)*rsqrtf(fmaxf(var,0.f)+1e-5f)*ldg_(ln_g,t,bf) + ldg_(ln_b,t,bf);
      float p_acc = ldg_(bp, t, bf);
      const u16* Wpp = gw + GWP + t;
      #pragma unroll 16
      for(int k=0;k<64;k++) p_acc += efL[k]*bf2f(Wpp[k*64]);
      prL[t] = p_acc;
    }
    {
      int part = t>>3, e = t&7;
      float gp = 0.f;
      const u16* Wgp = gw + GWG + e;
      #pragma unroll
      for(int i=0;i<8;i++){
        int k = part*8 + i;
        gp += latL[k]*bf2f(Wgp[k*8]);
      }
      lgpart[part][e] = gp;
    }
    __syncthreads();                              // S3
    {
      int p = t>>4, q4 = t&15;
      float dd = 0.f;
      #pragma unroll
      for(int i=0;i<4;i++){
        int d = q4*4 + i;
        float df = prL[d] - bf2f(gw[GPROT + p*64 + d]);
        dd += df*df;
      }
      d2part[p][q4] = dd;
    }
    __syncthreads();                              // S4
    if(t < 16){
      float s = 0.f;
      #pragma unroll
      for(int i=0;i<16;i++) s += d2part[t][i];
      d2s[t] = s;
    }
    __syncthreads();                              // S5
    if(t < 8){
      float g = ldg_(bg, t, bf);
      #pragma unroll
      for(int p=0;p<32;p++) g += lgpart[p][t];
      float d2pe = fminf(d2s[2*t], d2s[2*t+1]);   // NPROT/E = 2
      float temp = fminf(fmaxf(__expf(ldg_(log_temp,0,bf)), 0.1f), 10.f);
      float v = (g - d2pe) / temp;
      float m = v;
      m = fmaxf(m, __shfl_xor(m,1));
      m = fmaxf(m, __shfl_xor(m,2));
      m = fmaxf(m, __shfl_xor(m,4));
      float ex = __expf(v-m);
      float sum = ex;
      sum += __shfl_xor(sum,1);
      sum += __shfl_xor(sum,2);
      sum += __shfl_xor(sum,4);
      wgt[b*8+t] = ex/sum;
    }
    return;
  }
  // ---------------- k5b (f GEMM + decay epilogue) ----------------
  {
    int bx = BX - 32;
    int e = bx >> 7, inner = bx & 127;
    int b = inner >> 2, half = (inner >> 1) & 1, cb = inner & 1;
    int row0 = b*512 + half*128;
    int col0 = cb*128;
    int w = t >> 6, lane = t & 63, quad = lane >> 4, l15 = lane & 15;

    if(t < 128){
      int c = col0 + t;
      biasS[t] = ldg_(b_in, e*256+c, bf) + ldg_(b_fft, e*256+c, bf);
      float a = 1.f/(1.f+__expf(-ldg_(a_logit, e*256+c, bf)));
      a = fminf(fmaxf(a, 1e-12f), 0.99999988f);
      aS[t] = a;
      l2aS[t] = FLOG2(a);
    }
    const u16* Ab = hmagG + (long long)((e<<6)|(b<<1)|half)*32768;
    const f4v zf = (f4v){0.f,0.f,0.f,0.f};
    f4v acc[2][8];
    #pragma unroll
    for(int mt=0;mt<2;mt++)
      #pragma unroll
      for(int nt=0;nt<8;nt++) acc[mt][nt] = zf;

    for(int kc=0;kc<4;kc++){
      int k0 = kc*64;
      __syncthreads();
      #pragma unroll
      for(int q=0;q<4;q++){
        int G = q*256 + t;
        int c = G >> 3, k8 = (G & 7)*8;
        *(s8v*)&BsT[c][k8] = *(const s8v*)(WfftTg + ((long long)e*256 + col0 + c)*256 + k0 + k8);
      }
      __syncthreads();
      #pragma unroll
      for(int ks=0;ks<2;ks++){
        int kb = ks*32 + quad*8;
        s8v aF0 = *(const s8v*)(Ab + (w*32 + l15)*256 + k0 + kb);
        s8v aF1 = *(const s8v*)(Ab + (w*32 + 16 + l15)*256 + k0 + kb);
        #pragma unroll
        for(int nt=0;nt<8;nt++){
          s8v bF = *(const s8v*)&BsT[nt*16 + l15][kb];
          acc[0][nt] = MFMA_BF16(aF0, bF, acc[0][nt]);
          acc[1][nt] = MFMA_BF16(aF1, bF, acc[1][nt]);
        }
      }
    }
    // epilogue: apply f to original rows l and mirror rows 512-l
    s8v xF[2], xFm[2];
    #pragma unroll
    for(int mt=0;mt<2;mt++){
      long long rowO = (long long)row0 + w*32 + mt*16 + l15;
      xF[mt] = *(const s8v*)(xbf + rowO*32 + quad*8);
      int lin = half*128 + w*32 + mt*16 + l15;
      int lm  = (512 - lin) & 511;
      xFm[mt] = *(const s8v*)(xbf + ((long long)b*512 + lm)*32 + quad*8);
    }
    int l0base = half*128 + w*32 + quad*4;
    float mz = (l0base == 0) ? 0.f : 1.f;
    const f4v zf2 = (f4v){0.f,0.f,0.f,0.f};
    float part[8];
    #pragma unroll
    for(int nt=0;nt<8;nt++){
      s8v wfh = *(const s8v*)(WinTg + ((long long)e*256 + col0 + nt*16 + l15)*32 + quad*8);
      f4v hv0 = MFMA_BF16(xF[0],  wfh, zf2);
      f4v hv1 = MFMA_BF16(xF[1],  wfh, zf2);
      f4v hm0 = MFMA_BF16(xFm[0], wfh, zf2);
      f4v hm1 = MFMA_BF16(xFm[1], wfh, zf2);
      int cl = nt*16 + l15;
      float l2a = l2aS[cl], bias = biasS[cl], av = aS[cl];
      float inv_a = FEXP2(-l2a);
      float cO0 = FEXP2(l2a * (float)(511 - l0base));
      float cO1 = FEXP2(l2a * (float)(495 - l0base));
      float cM0 = FEXP2(l2a * (float)(l0base - 1));
      float cM1 = FEXP2(l2a * (float)(l0base + 15));
      float sum = 0.f;
      #pragma unroll
      for(int r=0;r<4;r++){
        float u0 = fmaxf(acc[0][nt][r] + hv0[r] + bias, 0.f);
        sum += u0 * cO0;
        float u1 = fmaxf(acc[1][nt][r] + hv1[r] + bias, 0.f);
        sum += u1 * cO1;
        float m0 = fmaxf(acc[0][nt][r] + hm0[r] + bias, 0.f);
        float w0 = m0 * cM0;
        if(r == 0) w0 *= mz;
        sum += w0;
        float m1 = fmaxf(acc[1][nt][r] + hm1[r] + bias, 0.f);
        sum += m1 * cM1;
        cO0 *= inv_a; cO1 *= inv_a; cM0 *= av; cM1 *= av;
      }
      part[nt] = sum;
    }
    __syncthreads();
    float (*redS)[132] = (float(*)[132])BsT;
    #pragma unroll
    for(int nt=0;nt<8;nt++)
      redS[w*4 + quad][nt*16 + l15] = part[nt];
    __syncthreads();
    if(t < 128){
      float tot = 0.f;
      #pragma unroll
      for(int i=0;i<16;i++) tot += redS[i][t];
      sp[e*16384 + (b*2 + half)*256 + col0 + t] = tot;
    }
  }
}

// ---------------------------------------------------------------------------
// K6 v3 (e-parallel, ss built in LDS): each block builds its expert's
// ss[32][256] tile from sp/contrib/(1-a) (same f2bf rounding as the old
// ssbf), runs 32 MFMA vs WheadTg[e], stores raw yaccE[e]. grid (24,8).
// ---------------------------------------------------------------------------
__global__ __launch_bounds__(256) void k6_mfma(const void* __restrict__ ln_g,
    const float* __restrict__ sp, const float* __restrict__ contrib,
    const void* __restrict__ a_logit,
    const u16* __restrict__ WheadTg, float* __restrict__ yaccE){
  const bool bf = bfflag(ln_g);
  int nb = blockIdx.x, e = blockIdx.y;
  int t = threadIdx.x;
  int w = t >> 6, lane = t & 63, quad = lane >> 4, l15 = lane & 15;
  __shared__ __align__(16) u16 ssS[32][264];   // row stride 528B (16B-aligned)
  // build ss tile: thread t owns column k=t across the 32 batch rows
  {
    float a = 1.f/(1.f+__expf(-ldg_(a_logit, e*256+t, bf)));
    a = fminf(fmaxf(a, 1e-12f), 0.99999988f);
    float oma = 1.f - a;
    const float* sp0 = sp + e*16384 + t;
    const float* cb  = contrib + e*8192 + t;
    #pragma unroll
    for(int q=0;q<32;q++){
      float v = oma*(sp0[q*512] + sp0[q*512+256] + cb[q*256]);
      ssS[q][t] = f2bf(v);
    }
  }
  __syncthreads();
  const f4v zf = (f4v){0.f,0.f,0.f,0.f};
  f4v acc[2][2];
  #pragma unroll
  for(int mt=0;mt<2;mt++)
    #pragma unroll
    for(int nt=0;nt<2;nt++) acc[mt][nt] = zf;
  #pragma unroll
  for(int ks=0;ks<8;ks++){
    int k = ks*32 + quad*8;
    s8v aF0 = *(const s8v*)&ssS[l15][k];
    s8v aF1 = *(const s8v*)&ssS[16 + l15][k];
    s8v bF[2];
    #pragma unroll
    for(int nt=0;nt<2;nt++)
      bF[nt] = *(const s8v*)(WheadTg + ((long long)e*3072 + nb*128 + w*32 + nt*16 + l15)*256 + k);
    acc[0][0] = MFMA_BF16(aF0, bF[0], acc[0][0]);
    acc[0][1] = MFMA_BF16(aF0, bF[1], acc[0][1]);
    acc[1][0] = MFMA_BF16(aF1, bF[0], acc[1][0]);
    acc[1][1] = MFMA_BF16(aF1, bF[1], acc[1][1]);
  }
  float* yo = yaccE + (long long)e*98304;
  #pragma unroll
  for(int mt=0;mt<2;mt++)
    #pragma unroll
    for(int nt=0;nt<2;nt++){
      int col = nb*128 + w*32 + nt*16 + l15;
      #pragma unroll
      for(int r=0;r<4;r++){
        int b = mt*16 + quad*4 + r;
        yo[b*3072 + col] = acc[mt][nt][r];
      }
    }
}

// K7: out[b,col] = sum_e wgt[b,e]*(yaccE[e,b,col] + b_head[e,col]). grid 384.
__global__ void k7_out(const void* __restrict__ ln_g,
                       const float* __restrict__ yaccE,
                       const float* __restrict__ wgt,
                       const void* __restrict__ b_head,
                       void* __restrict__ out){
  const bool bf = bfflag(ln_g);
  int i = blockIdx.x*256 + threadIdx.x;
  int b = i / 3072, col = i - b*3072;
  float v = 0.f;
  #pragma unroll
  for(int e=0;e<8;e++)
    v += wgt[b*8+e]*(yaccE[(long long)e*98304 + i] + ldg_(b_head, (long long)e*3072+col, bf));
  if(bf) ((u16*)out)[i] = f2bf(v);
  else   ((float*)out)[i] = v;
}

// ---------------------------------------------------------------------------
extern "C" void kernel_launch(void* const* d_in, const int* in_sizes, int n_in,
                              void* d_out, int out_size, void* d_ws, size_t ws_size,
                              hipStream_t stream){
  const void* x       = d_in[0];
  const void* prot    = d_in[1];
  const void* Wp      = d_in[2];
  const void* bp      = d_in[3];
  const void* Wf1     = d_in[4];
  const void* bf1     = d_in[5];
  const void* Wf2     = d_in[6];
  const void* bf2     = d_in[7];
  const void* ln_g    = d_in[8];
  const void* ln_b    = d_in[9];
  const void* W1      = d_in[10];
  const void* b1      = d_in[11];
  const void* W2      = d_in[12];
  const void* b2      = d_in[13];
  const void* Wg      = d_in[14];
  const void* bg      = d_in[15];
  const void* log_temp= d_in[16];
  const void* Win     = d_in[17];
  const void* b_in    = d_in[18];
  const void* Wfft    = d_in[19];
  const void* b_fft   = d_in[20];
  const void* a_logit = d_in[21];
  const void* Whead   = d_in[22];
  const void* b_head  = d_in[23];

  // ws layout: ~65 MB
  float* ws      = (float*)d_ws;
  float* cf      = ws;                       // 7168
  float* wgt     = cf + 7168;                // 256
  float* sp      = wgt + 256;                // 131072
  float* h1f     = sp + 131072;              // 8192
  float* contrib = h1f + 8192;               // 65536 (8 x 32 x 256 fp32)
  float* psum    = contrib + 65536;          // 524288
  float* yaccE   = psum + 524288;            // 786432 (8 x 32 x 3072 fp32)
  u16*   Xr      = (u16*)(yaccE + 786432);   // 524288 bf16 (bins 0..256 used)
  u16*   Xi      = Xr + 524288;              // 524288
  u16*   xbf     = Xi + 524288;              // 524288
  u16*   WinTg   = xbf + 524288;             // 65536
  u16*   WfftTg  = WinTg + 65536;            // 524288
  u16*   W1Tg    = WfftTg + 524288;          // 4194304
  u16*   WheadTg = W1Tg + 4194304;           // 6291456
  u16*   gw      = WheadTg + 6291456;        // 146432
  u16*   hmagG   = gw + 146432;              // 16777216 (8*64*128*256 bf16)

  ks1 <<<dim3(4623), dim3(256), 0, stream>>>(ln_g, x, Win, Wfft, W1, Whead,
                                             Wf1, W2, Wf2, Wp, prot, Wg,
                                             xbf, WinTg, WfftTg, W1Tg, WheadTg, gw,
                                             Xr, Xi, cf);
  ks2 <<<dim3(1376), dim3(256), 0, stream>>>(ln_g, xbf, Xr, Xi, WinTg, W1Tg,
                                             gw, cf, bf1, b_in, b_fft, a_logit,
                                             Win, Wfft,
                                             psum, hmagG, h1f, contrib);
  ks3 <<<dim3(1056), dim3(256), 0, stream>>>(ln_g, psum, h1f, gw,
                                             b1, bf2, ln_b, bp, b2, bg, log_temp,
                                             xbf, hmagG, WinTg, WfftTg,
                                             b_in, b_fft, a_logit,
                                             wgt, sp);
  k6_mfma <<<dim3(24,8), dim3(256), 0, stream>>>(ln_g, sp, contrib, a_logit,
                                                 WheadTg, yaccE);
  k7_out  <<<dim3(384),  dim3(256), 0, stream>>>(ln_g, yaccE, wgt, b_head, d_out);
}